// Round 1
// baseline (970.317 us; speedup 1.0000x reference)
//
#include <hip/hip_runtime.h>
#include <stdint.h>

typedef __attribute__((ext_vector_type(8))) short short8;
typedef __attribute__((ext_vector_type(4))) short short4v;
typedef __attribute__((ext_vector_type(4))) float floatx4;

#define LDQ 136   // 128 + 8 bf16 pad -> 272B rows, 16B aligned

__device__ __forceinline__ uint16_t f32_to_bf16(float f) {
    uint32_t u = __builtin_bit_cast(uint32_t, f);
    u += 0x7FFFu + ((u >> 16) & 1u);   // RTNE
    return (uint16_t)(u >> 16);
}

__device__ __forceinline__ floatx4 mfma16x16x16_bf16(short4v a, short4v b, floatx4 c) {
#if __has_builtin(__builtin_amdgcn_mfma_f32_16x16x16bf16_1k)
    return __builtin_amdgcn_mfma_f32_16x16x16bf16_1k(a, b, c, 0, 0, 0);
#else
    floatx4 d;
    asm volatile("v_mfma_f32_16x16x16_bf16 %0, %1, %2, %3"
                 : "=v"(d) : "v"(a), "v"(b), "v"(c));
    return d;
#endif
}

// ---------------- Kernel 1: Householder Q, one wave per column ----------------
__global__ __launch_bounds__(256) void hh_q_kernel(const float* __restrict__ vs,
                                                   uint16_t* __restrict__ Qrm,
                                                   uint16_t* __restrict__ Qt) {
    __shared__ float vsl[64 * 128];   // 32 KB
    int tid = threadIdx.x;
    const float4* vsv = (const float4*)vs;
    float4* vslv = (float4*)vsl;
#pragma unroll
    for (int i = 0; i < 8; ++i) vslv[tid + 256 * i] = vsv[tid + 256 * i];
    __syncthreads();

    int wave = tid >> 6, lane = tid & 63;
    int col = blockIdx.x * 4 + wave;          // 32 blocks * 4 waves = 128 cols
    float x0 = (lane == col) ? 1.f : 0.f;
    float x1 = (lane + 64 == col) ? 1.f : 0.f;
    for (int k = 0; k < 64; ++k) {
        float v0 = vsl[k * 128 + lane];
        float v1 = vsl[k * 128 + 64 + lane];
        float d  = v0 * x0 + v1 * x1;
        float vn = v0 * v0 + v1 * v1;
#pragma unroll
        for (int m = 1; m < 64; m <<= 1) {
            d  += __shfl_xor(d, m, 64);
            vn += __shfl_xor(vn, m, 64);
        }
        float sfac = 2.f / (vn + 1e-8f) * d;
        x0 -= sfac * v0;
        x1 -= sfac * v1;
    }
    Qrm[lane * 128 + col]        = f32_to_bf16(x0);
    Qrm[(lane + 64) * 128 + col] = f32_to_bf16(x1);
    Qt[col * 128 + lane]         = f32_to_bf16(x0);   // Qt[a][b] = Q[b][a]
    Qt[col * 128 + lane + 64]    = f32_to_bf16(x1);
}

// ---------------- Kernel 2: fused (x @ Q^T) -> RoPE -> (@ Q) ----------------
// Swapped-operand GEMM1: acc[nt][r] = C1[m=x][d=16*nt+4*g+r]  (lane owns s-row x).
// RoPE pairs (d, d+64) live in acc[nt]/acc[nt+4], same reg index r -> float4 cos/sin.
// Lane's d-residency {4g+r mod 16} == B-fragment layout of mfma 16x16x16 ->
// GEMM2 (outT = Q^T * P^T) needs NO shuffle / NO LDS scratch / NO barrier.
// GEMM2 C-layout: lane holds out[m=x][e=16*nte+4g+r] -> float4 stores.
__global__ __launch_bounds__(512, 4) void rope_rot_kernel(
    const float* __restrict__ qin, const float* __restrict__ kin,
    const float* __restrict__ cosp, const float* __restrict__ sinp,
    const uint16_t* __restrict__ Qrm, const uint16_t* __restrict__ Qt,
    float* __restrict__ outp) {

    __shared__ uint16_t Qlds[128 * LDQ];    // 34816 B   Q row-major
    __shared__ uint16_t Qtlds[128 * LDQ];   // 34816 B   Q^T row-major

    int tid = threadIdx.x;
    {   // stage both matrices once per block; 16B chunks, coalesced
        const short8* qg = (const short8*)Qrm;
        const short8* tg = (const short8*)Qt;
#pragma unroll
        for (int i = 0; i < 4; ++i) {
            int e8 = tid + i * 512;          // 2048 chunks of 8 bf16
            int row = e8 >> 4;
            int col = (e8 & 15) * 8;
            *(short8*)&Qlds[row * LDQ + col]  = qg[e8];
            *(short8*)&Qtlds[row * LDQ + col] = tg[e8];
        }
    }
    __syncthreads();   // the ONLY barrier in the kernel

    int wave = tid >> 6, lane = tid & 63;
    int x = lane & 15, g = lane >> 4;
    int wg = blockIdx.x * 8 + wave;          // 512 blocks * 8 waves = 4096
    int bs = wg >> 2;                        // b*256 + s16
    int b = bs >> 8, s16 = bs & 255;
    int hg = wg & 3;                         // h quad: 4 h-values per wave

    long csoff = ((long)(b * 4096 + s16 * 16 + x)) * 128 + 4 * g;
    const float* cbase = cosp + csoff;       // float4-aligned, L1-hot across l-loop
    const float* sbase = sinp + csoff;

#pragma unroll 1
    for (int l = 0; l < 8; ++l) {            // 4 h * 2 tensors, shared cos/sin tile
        int h = hg * 4 + (l >> 1);
        int t = l & 1;
        long rowbase = ((long)(b * 16 + h)) * 4096 + s16 * 16;
        const float* src  = t ? kin : qin;
        const float* arow = src + (rowbase + x) * 128 + 8 * g;

        floatx4 zero4 = {0.f, 0.f, 0.f, 0.f};
        floatx4 acc[8];
#pragma unroll
        for (int nt = 0; nt < 8; ++nt) acc[nt] = zero4;

        // ---- GEMM1 (swapped): acc[nt][r] = sum_k q[x][k]*Q[16nt+4g+r][k] ----
#pragma unroll
        for (int kt = 0; kt < 4; ++kt) {
            floatx4 a0 = *(const floatx4*)(arow + kt * 32);
            floatx4 a1 = *(const floatx4*)(arow + kt * 32 + 4);
            short8 af;
#pragma unroll
            for (int j = 0; j < 4; ++j) {
                af[j]     = (short)f32_to_bf16(a0[j]);
                af[j + 4] = (short)f32_to_bf16(a1[j]);
            }
#pragma unroll
            for (int nt = 0; nt < 8; ++nt) {
                short8 qf = *(const short8*)&Qlds[(nt * 16 + x) * LDQ + kt * 32 + 8 * g];
                acc[nt] = __builtin_amdgcn_mfma_f32_16x16x32_bf16(qf, af, acc[nt], 0, 0, 0);
            }
        }

        // ---- RoPE in-register, vectorized cos/sin, pack to K=16 B-fragments ----
        short4v pb[8];
#pragma unroll
        for (int nt = 0; nt < 4; ++nt) {
            floatx4 cl = *(const floatx4*)(cbase + nt * 16);
            floatx4 ch = *(const floatx4*)(cbase + (nt + 4) * 16);
            floatx4 sl = *(const floatx4*)(sbase + nt * 16);
            floatx4 sh = *(const floatx4*)(sbase + (nt + 4) * 16);
            short4v lo, hi;
#pragma unroll
            for (int r = 0; r < 4; ++r) {
                float vlo = acc[nt][r] * cl[r] - acc[nt + 4][r] * sl[r];
                float vhi = acc[nt + 4][r] * ch[r] + acc[nt][r] * sh[r];
                lo[r] = (short)f32_to_bf16(vlo);
                hi[r] = (short)f32_to_bf16(vhi);
            }
            pb[nt] = lo;
            pb[nt + 4] = hi;
        }

        // ---- GEMM2: out^T = Q^T P^T via 8x8 K=16 MFMAs, P straight from regs ----
        floatx4 acc2[8];
#pragma unroll
        for (int nt = 0; nt < 8; ++nt) acc2[nt] = zero4;
#pragma unroll
        for (int ntk = 0; ntk < 8; ++ntk) {
#pragma unroll
            for (int nte = 0; nte < 8; ++nte) {
                short4v a4 = *(const short4v*)&Qtlds[(nte * 16 + x) * LDQ + ntk * 16 + 4 * g];
                acc2[nte] = mfma16x16x16_bf16(a4, pb[ntk], acc2[nte]);
            }
        }

        // ---- float4 stores: lane holds out[m=x][e=16*nte+4g..+3] ----
        float* obase = outp + (long)t * 33554432L + (rowbase + x) * 128 + 4 * g;
#pragma unroll
        for (int nte = 0; nte < 8; ++nte) {
            *(floatx4*)(obase + nte * 16) = acc2[nte];
        }
    }
}

extern "C" void kernel_launch(void* const* d_in, const int* in_sizes, int n_in,
                              void* d_out, int out_size, void* d_ws, size_t ws_size,
                              hipStream_t stream) {
    const float* q   = (const float*)d_in[0];
    const float* k   = (const float*)d_in[1];
    const float* cs  = (const float*)d_in[2];
    const float* sn  = (const float*)d_in[3];
    const float* vs  = (const float*)d_in[4];
    uint16_t* Qrm = (uint16_t*)d_ws;           // 128*128 bf16
    uint16_t* Qt  = Qrm + 128 * 128;           // transposed copy

    hh_q_kernel<<<32, 256, 0, stream>>>(vs, Qrm, Qt);
    // 512 blocks * 8 waves, 8 (h,t)-tiles per wave: Q/Qt staged once, zero
    // main-loop barriers, cos/sin tile L1-resident across the 8 tiles.
    rope_rot_kernel<<<512, 512, 0, stream>>>(q, k, cs, sn, Qrm, Qt, (float*)d_out);
}